// Round 5
// baseline (7188.206 us; speedup 1.0000x reference)
//
#include <hip/hip_runtime.h>

#define NN 256
#define INFV 1e30f

// ---- mask format handling (bool may arrive as bytes, int32, or float32) ----
__device__ __forceinline__ int mask_fmt(const void* m) {
    int w0 = ((const int*)m)[0];          // mask[0][0] is always true (lengths >= N/2)
    if (w0 == 1) return 0;                // int32 0/1
    if (w0 == 0x3F800000) return 1;       // float32 1.0f
    return 2;                             // 1-byte bool
}
__device__ __forceinline__ bool mask_at(const void* m, int fmt, int idx) {
    if (fmt == 0) return ((const int*)m)[idx] != 0;
    if (fmt == 1) return ((const float*)m)[idx] != 0.0f;
    return ((const unsigned char*)m)[idx] != 0;
}

// ---- tiled transpose + mask: ws[b][i][j] = mask[b][i] ? costs[b][j][i] : 0 ----
__global__ void transpose_mask_kernel(const float* __restrict__ costs,
                                      const void* __restrict__ mask,
                                      float* __restrict__ ws) {
    __shared__ float tile[32][33];
    const int b  = blockIdx.z;
    const int i0 = blockIdx.x * 32;
    const int j0 = blockIdx.y * 32;
    const int tx = threadIdx.x;   // 0..31
    const int ty = threadIdx.y;   // 0..7
    const int fmt = mask_fmt(mask);
    const float* Cb = costs + (size_t)b * NN * NN;
    float* Wb = ws + (size_t)b * NN * NN;

    #pragma unroll
    for (int k = 0; k < 32; k += 8) {
        tile[ty + k][tx] = Cb[(size_t)(j0 + ty + k) * NN + (i0 + tx)];
    }
    __syncthreads();
    #pragma unroll
    for (int k = 0; k < 32; k += 8) {
        const int i = i0 + ty + k;
        const int j = j0 + tx;
        const bool mv = mask_at(mask, fmt, b * NN + i);
        Wb[(size_t)i * NN + j] = mv ? tile[tx][ty + k] : 0.0f;
    }
}

// ---------- cross-lane helpers ----------
__device__ __forceinline__ int rl(int v, int lane) {
    return __builtin_amdgcn_readlane(v, lane);
}
__device__ __forceinline__ float rlf(float v, int lane) {
    return __int_as_float(__builtin_amdgcn_readlane(__float_as_int(v), lane));
}
// read element idx (uniform, 0..255) from a distributed array: lane k holds elems 4k..4k+3
__device__ __forceinline__ int read4i(const int a[4], int idx) {
    const int lane = idx >> 2;
    const int v0 = rl(a[0], lane), v1 = rl(a[1], lane);
    const int v2 = rl(a[2], lane), v3 = rl(a[3], lane);
    const int lo = (idx & 1) ? v1 : v0;
    const int hi = (idx & 1) ? v3 : v2;
    return (idx & 2) ? hi : lo;
}
__device__ __forceinline__ float read4f(const float a[4], int idx) {
    const int lane = idx >> 2;
    const int v0 = rl(__float_as_int(a[0]), lane), v1 = rl(__float_as_int(a[1]), lane);
    const int v2 = rl(__float_as_int(a[2]), lane), v3 = rl(__float_as_int(a[3]), lane);
    const int lo = (idx & 1) ? v1 : v0;
    const int hi = (idx & 1) ? v3 : v2;
    return __int_as_float((idx & 2) ? hi : lo);
}
// write val to distributed array element idx (idx uniform)
__device__ __forceinline__ void write4i(int (&a)[4], int idx, int val, int lane) {
    if (lane == (idx >> 2)) {
        switch (idx & 3) {
            case 0: a[0] = val; break;
            case 1: a[1] = val; break;
            case 2: a[2] = val; break;
            default: a[3] = val; break;
        }
    }
}

// DPP move: result = src from DPP-selected lane; lanes with no valid source keep old(=x)
template <int CTRL>
__device__ __forceinline__ float dpp_mov_f(float x) {
    return __int_as_float(__builtin_amdgcn_update_dpp(
        __float_as_int(x), __float_as_int(x), CTRL, 0xf, 0xf, false));
}
// full-wave min: row_shr 1,2,4,8 accumulates toward lane 15/31/47/63 of each 16-row;
// row_bcast:15 merges row pairs, row_bcast:31 merges halves (lane 63 <- global min).
__device__ __forceinline__ float wave_min64(float x) {
    x = fminf(x, dpp_mov_f<0x111>(x));  // row_shr:1
    x = fminf(x, dpp_mov_f<0x112>(x));  // row_shr:2
    x = fminf(x, dpp_mov_f<0x114>(x));  // row_shr:4
    x = fminf(x, dpp_mov_f<0x118>(x));  // row_shr:8
    x = fminf(x, dpp_mov_f<0x142>(x));  // row_bcast:15
    x = fminf(x, dpp_mov_f<0x143>(x));  // row_bcast:31
    return rlf(x, 63);
}

// ---- exact JV LAP, one block (1 wave, 64 lanes) per batch, 4 cols/lane ----
// rcache = leading rows of the (transposed+masked) cost matrix held in dynamic LDS.
template <bool USE_WS>
__global__ __launch_bounds__(64)
void lap_kernel(const float* __restrict__ costs,
                const void* __restrict__ mask,
                const float* __restrict__ cmat,
                int* __restrict__ out,
                int rcache) {
    extern __shared__ float ldsrows[];   // [rcache][NN]

    const int b    = blockIdx.x;
    const int lane = threadIdx.x;   // lane owns rows/cols lane*4 .. lane*4+3

    __shared__ float sp_s[NN];
    __shared__ int   tmp_s[NN];

    const int fmt = mask_fmt(mask);

    // n = count of valid objects (mask is prefix-true)
    int nloc = 0;
    #pragma unroll
    for (int r = 0; r < 4; ++r)
        nloc += mask_at(mask, fmt, b * NN + lane * 4 + r) ? 1 : 0;
    #pragma unroll
    for (int off = 32; off; off >>= 1) nloc += __shfl_xor(nloc, off);
    const int n = nloc;

    // distributed state (registers): lane k holds element 4k+r
    float u[4]  = {0.f, 0.f, 0.f, 0.f};   // row potentials
    float v[4]  = {0.f, 0.f, 0.f, 0.f};   // col potentials
    int  c4r[4] = {-1, -1, -1, -1};       // col4row (by row)
    int  r4c[4] = {-1, -1, -1, -1};       // row4col (by col)

    const float* CM = cmat + (size_t)b * NN * NN;   // transposed+masked
    const float* CB = costs + (size_t)b * NN * NN;  // raw (fallback)

    // row loader: LDS if cached, else global (wave-uniform scalar branch)
    auto load_row = [&](int irow, float (&cc)[4]) {
        if (USE_WS) {
            if (irow < rcache) {
                const float4 c4 = *reinterpret_cast<const float4*>(&ldsrows[irow * NN + lane * 4]);
                cc[0] = c4.x; cc[1] = c4.y; cc[2] = c4.z; cc[3] = c4.w;
            } else {
                const float4 c4 = *reinterpret_cast<const float4*>(CM + (size_t)irow * NN + lane * 4);
                cc[0] = c4.x; cc[1] = c4.y; cc[2] = c4.z; cc[3] = c4.w;
            }
        } else {
            if (irow < n) {
                #pragma unroll
                for (int r = 0; r < 4; ++r)
                    cc[r] = CB[(size_t)(lane * 4 + r) * NN + irow];
            } else {
                #pragma unroll
                for (int r = 0; r < 4; ++r) cc[r] = 0.0f;
            }
        }
    };

    // ---- prologue: stage leading rows into LDS ----
    if (USE_WS) {
        #pragma unroll 4
        for (int row = 0; row < rcache; ++row) {
            const int base = row * NN + lane * 4;
            *reinterpret_cast<float4*>(&ldsrows[base]) =
                *reinterpret_cast<const float4*>(CM + base);
        }
        __syncthreads();
    }

    for (int cur = 0; cur < NN; ++cur) {
        // ---- Dijkstra shortest augmenting path (value-exact vs reference) ----
        float sp[4]    = {INFV, INFV, INFV, INFV};  // shortest-path costs (frozen once SC)
        float mreg[4]  = {INFV, INFV, INFV, INFV};  // masked sp (INF where SC) from prev iter
        float scadd[4] = {0.f, 0.f, 0.f, 0.f};      // 0 normal, INFV once column scanned
        int  path[4]   = {-1, -1, -1, -1};
        int   SCm = 0, SRm = 0;           // per-lane 4-bit masks
        int   i      = cur;               // wave-uniform
        float minVal = 0.0f;              // wave-uniform
        float Vprev  = INFV;              // min over masked sp from previous iteration
        int   sink   = -1;

        float cc[4];
        load_row(i, cc);                  // software-pipelined: reloaded at loop bottom

        // terminates within NN iterations (each adds a col to SC and an unmatched
        // col always exists); guard turns bugs into wrong answers, never hangs.
        for (int guard = 0; guard <= NN && sink < 0; ++guard) {
            if (lane == (i >> 2)) SRm |= 1 << (i & 3);
            const float u_i = read4f(u, i);   // uniform scalar (overlaps load wait)

            float rrm[4], m[4];
            #pragma unroll
            for (int r = 0; r < 4; ++r) {
                // exact reference op order: ((minVal + c) - u_i) - v_j
                const float rr = minVal + cc[r] - u_i - v[r];
                // SC-masking: rr + 1e30 == 1e30 exactly (|rr| << ulp(1e30));
                // equals reference's where(SC, INF, .) in every comparison.
                rrm[r] = rr + scadd[r];
            }
            // on-chain reduce: min over rrm only; combine with off-chain Vprev.
            // min(masked_sp_new) == fmin(min(rrm), min(masked_sp_old)) -- min assoc.
            minVal = fminf(wave_min64(fminf(fminf(rrm[0], rrm[1]), fminf(rrm[2], rrm[3]))),
                           Vprev);

            #pragma unroll
            for (int r = 0; r < 4; ++r) {
                const bool upd = rrm[r] < sp[r];     // strict <, false for SC (INF<sp)
                path[r] = upd ? i : path[r];
                sp[r]   = fminf(sp[r], rrm[r]);      // == where(upd, rr, sp)
                m[r]    = fminf(mreg[r], rrm[r]);    // masked sp after this iteration
            }

            // first column achieving minVal (== jnp.argmin on masked)
            const float lanem = fminf(fminf(m[0], m[1]), fminf(m[2], m[3]));
            const unsigned long long bal = __ballot(lanem == minVal);  // parallel w/ cand
            int cand = 4;
            if (m[3] == minVal) cand = 3;
            if (m[2] == minVal) cand = 2;
            if (m[1] == minVal) cand = 1;
            if (m[0] == minVal) cand = 0;
            const int fl = (bal == 0ull) ? 0 : (__ffsll((long long)bal) - 1);
            const int j  = (bal == 0ull) ? 0 : (fl * 4 + rl(cand, fl));

            if (lane == (j >> 2)) SCm |= 1 << (j & 3);
            #pragma unroll
            for (int r = 0; r < 4; ++r) {
                const bool isj = (lane * 4 + r) == j;
                mreg[r]  = isj ? INFV : m[r];
                scadd[r] = isj ? INFV : scadd[r];
            }

            // advance; issue next row load BEFORE the off-chain Vprev reduce so the
            // DPP chain's issue slots hide under the load latency.
            const int nxt = read4i(r4c, j);
            if (nxt < 0) {
                sink = j;
            } else {
                i = nxt;
                load_row(i, cc);
            }
            Vprev = wave_min64(fminf(fminf(mreg[0], mreg[1]), fminf(mreg[2], mreg[3])));
        }

        // dump sp for the dual-update gather (only per-outer LDS use)
        *reinterpret_cast<float4*>(&sp_s[lane * 4]) = make_float4(sp[0], sp[1], sp[2], sp[3]);
        __syncthreads();

        // ---- dual updates (select semantics, same elementwise ops as reference) ----
        #pragma unroll
        for (int r = 0; r < 4; ++r) {
            const int row = lane * 4 + r;
            if ((SRm >> r) & 1) {
                float du;
                if (row == cur) {
                    du = minVal;
                } else {
                    int c = c4r[r];
                    c = c < 0 ? 0 : c;            // clip like reference
                    du = minVal - sp_s[c];
                }
                u[r] = u[r] + du;
            }
            if ((SCm >> r) & 1) v[r] = v[r] - (minVal - sp[r]);
        }
        __syncthreads();

        // ---- augment along alternating path (wave-uniform walk, registers) ----
        {
            int j = sink;
            for (int guard = 0; guard < NN; ++guard) {
                const int ii = read4i(path, j);
                write4i(r4c, j, ii, lane);
                const int jn = read4i(c4r, ii);
                write4i(c4r, ii, j, lane);
                if (ii == cur) break;
                j = jn;
            }
        }
    }

    // ---- emit output ----
    int* ob = out + b * NN;
    #pragma unroll
    for (int r = 0; r < 4; ++r) {
        const int row = lane * 4 + r;
        if (row < n) ob[row] = c4r[r];
        tmp_s[lane * 4 + r] = r4c[r];
    }
    __syncthreads();
    if (lane == 0) {
        int cnt = 0;
        for (int c = 0; c < NN; ++c) {
            if (tmp_s[c] >= n) {      // column assigned to an invalid row => unused
                ob[n + cnt] = c;
                ++cnt;
            }
        }
    }
}

extern "C" void kernel_launch(void* const* d_in, const int* in_sizes, int n_in,
                              void* d_out, int out_size, void* d_ws, size_t ws_size,
                              hipStream_t stream) {
    const float* costs = (const float*)d_in[0];
    const void*  mask  = d_in[1];
    int*         out   = (int*)d_out;

    const int B = in_sizes[1] / NN;   // in_sizes[1] = B*N
    const size_t need = (size_t)B * NN * NN * sizeof(float);

    if (ws_size >= need && d_ws != nullptr) {
        float* ws = (float*)d_ws;
        transpose_mask_kernel<<<dim3(NN / 32, NN / 32, B), dim3(32, 8), 0, stream>>>(costs, mask, ws);

        // 158-row (158 KB) LDS row cache: 158*1024 + 2 KB static = 160 KB exactly.
        // hipFuncSetAttribute is host-side (graph-capture safe); fall back to 60
        // rows if rejected.
        int rcache = 158;
        hipError_t e = hipFuncSetAttribute(
            reinterpret_cast<const void*>(&lap_kernel<true>),
            hipFuncAttributeMaxDynamicSharedMemorySize,
            rcache * NN * (int)sizeof(float));
        if (e != hipSuccess) rcache = 60;
        const size_t dynbytes = (size_t)rcache * NN * sizeof(float);

        lap_kernel<true><<<dim3(B), dim3(64), dynbytes, stream>>>(costs, mask, ws, out, rcache);
    } else {
        lap_kernel<false><<<dim3(B), dim3(64), 0, stream>>>(costs, mask, nullptr, out, 0);
    }
}

// Round 6
// 6496.638 us; speedup vs baseline: 1.1065x; 1.1065x over previous
//
#include <hip/hip_runtime.h>

#define NN 256
#define INFV 1e30f

// ---- mask format handling (bool may arrive as bytes, int32, or float32) ----
__device__ __forceinline__ int mask_fmt(const void* m) {
    int w0 = ((const int*)m)[0];          // mask[0][0] is always true (lengths >= N/2)
    if (w0 == 1) return 0;                // int32 0/1
    if (w0 == 0x3F800000) return 1;       // float32 1.0f
    return 2;                             // 1-byte bool
}
__device__ __forceinline__ bool mask_at(const void* m, int fmt, int idx) {
    if (fmt == 0) return ((const int*)m)[idx] != 0;
    if (fmt == 1) return ((const float*)m)[idx] != 0.0f;
    return ((const unsigned char*)m)[idx] != 0;
}

// ---- tiled transpose + mask: ws[b][i][j] = mask[b][i] ? costs[b][j][i] : 0 ----
__global__ void transpose_mask_kernel(const float* __restrict__ costs,
                                      const void* __restrict__ mask,
                                      float* __restrict__ ws) {
    __shared__ float tile[32][33];
    const int b  = blockIdx.z;
    const int i0 = blockIdx.x * 32;
    const int j0 = blockIdx.y * 32;
    const int tx = threadIdx.x;   // 0..31
    const int ty = threadIdx.y;   // 0..7
    const int fmt = mask_fmt(mask);
    const float* Cb = costs + (size_t)b * NN * NN;
    float* Wb = ws + (size_t)b * NN * NN;

    #pragma unroll
    for (int k = 0; k < 32; k += 8) {
        tile[ty + k][tx] = Cb[(size_t)(j0 + ty + k) * NN + (i0 + tx)];
    }
    __syncthreads();
    #pragma unroll
    for (int k = 0; k < 32; k += 8) {
        const int i = i0 + ty + k;
        const int j = j0 + tx;
        const bool mv = mask_at(mask, fmt, b * NN + i);
        Wb[(size_t)i * NN + j] = mv ? tile[tx][ty + k] : 0.0f;
    }
}

// ---------- cross-lane helpers ----------
__device__ __forceinline__ int rl(int v, int lane) {
    return __builtin_amdgcn_readlane(v, lane);
}
__device__ __forceinline__ float rlf(float v, int lane) {
    return __int_as_float(__builtin_amdgcn_readlane(__float_as_int(v), lane));
}
// read element idx (uniform, 0..255) from a distributed array: lane k holds elems 4k..4k+3
__device__ __forceinline__ int read4i(const int a[4], int idx) {
    const int lane = idx >> 2;
    const int v0 = rl(a[0], lane), v1 = rl(a[1], lane);
    const int v2 = rl(a[2], lane), v3 = rl(a[3], lane);
    const int lo = (idx & 1) ? v1 : v0;
    const int hi = (idx & 1) ? v3 : v2;
    return (idx & 2) ? hi : lo;
}
__device__ __forceinline__ float read4f(const float a[4], int idx) {
    const int lane = idx >> 2;
    const int v0 = rl(__float_as_int(a[0]), lane), v1 = rl(__float_as_int(a[1]), lane);
    const int v2 = rl(__float_as_int(a[2]), lane), v3 = rl(__float_as_int(a[3]), lane);
    const int lo = (idx & 1) ? v1 : v0;
    const int hi = (idx & 1) ? v3 : v2;
    return __int_as_float((idx & 2) ? hi : lo);
}
// write val to distributed array element idx (idx uniform)
__device__ __forceinline__ void write4i(int (&a)[4], int idx, int val, int lane) {
    if (lane == (idx >> 2)) {
        switch (idx & 3) {
            case 0: a[0] = val; break;
            case 1: a[1] = val; break;
            case 2: a[2] = val; break;
            default: a[3] = val; break;
        }
    }
}

// DPP move: result = src from DPP-selected lane; lanes with no valid source keep old(=x)
template <int CTRL>
__device__ __forceinline__ float dpp_mov_f(float x) {
    return __int_as_float(__builtin_amdgcn_update_dpp(
        __float_as_int(x), __float_as_int(x), CTRL, 0xf, 0xf, false));
}
// full-wave min: row_shr 1,2,4,8 accumulates toward lane 15/31/47/63 of each 16-row;
// row_bcast:15 merges row pairs, row_bcast:31 merges halves (lane 63 <- global min).
__device__ __forceinline__ float wave_min64(float x) {
    x = fminf(x, dpp_mov_f<0x111>(x));  // row_shr:1
    x = fminf(x, dpp_mov_f<0x112>(x));  // row_shr:2
    x = fminf(x, dpp_mov_f<0x114>(x));  // row_shr:4
    x = fminf(x, dpp_mov_f<0x118>(x));  // row_shr:8
    x = fminf(x, dpp_mov_f<0x142>(x));  // row_bcast:15
    x = fminf(x, dpp_mov_f<0x143>(x));  // row_bcast:31
    return rlf(x, 63);
}

// ---- exact JV LAP, one block (1 wave, 64 lanes) per batch, 4 cols/lane ----
// rcache = leading rows of the (transposed+masked) cost matrix held in dynamic LDS.
template <bool USE_WS>
__global__ __launch_bounds__(64)
void lap_kernel(const float* __restrict__ costs,
                const void* __restrict__ mask,
                const float* __restrict__ cmat,
                int* __restrict__ out,
                int rcache) {
    extern __shared__ float ldsrows[];   // [rcache][NN]

    const int b    = blockIdx.x;
    const int lane = threadIdx.x;   // lane owns rows/cols lane*4 .. lane*4+3

    __shared__ float sp_s[NN];
    __shared__ int   tmp_s[NN];

    const int fmt = mask_fmt(mask);

    // n = count of valid objects (mask is prefix-true)
    int nloc = 0;
    #pragma unroll
    for (int r = 0; r < 4; ++r)
        nloc += mask_at(mask, fmt, b * NN + lane * 4 + r) ? 1 : 0;
    #pragma unroll
    for (int off = 32; off; off >>= 1) nloc += __shfl_xor(nloc, off);
    const int n = nloc;

    // distributed state (registers): lane k holds element 4k+r
    float u[4]  = {0.f, 0.f, 0.f, 0.f};   // row potentials
    float v[4]  = {0.f, 0.f, 0.f, 0.f};   // col potentials
    int  c4r[4] = {-1, -1, -1, -1};       // col4row (by row)
    int  r4c[4] = {-1, -1, -1, -1};       // row4col (by col)

    const float* CM = cmat + (size_t)b * NN * NN;   // transposed+masked
    const float* CB = costs + (size_t)b * NN * NN;  // raw (fallback)

    // row loader. rows >= n are exactly zero in CM (mask is prefix-true), so skip
    // the memory access entirely for them (uniform scalar branch on readlane'd i).
    auto load_row = [&](int irow, float (&cc)[4]) {
        if (USE_WS) {
            if (irow >= n) {
                cc[0] = cc[1] = cc[2] = cc[3] = 0.0f;
            } else if (irow < rcache) {
                const float4 c4 = *reinterpret_cast<const float4*>(&ldsrows[irow * NN + lane * 4]);
                cc[0] = c4.x; cc[1] = c4.y; cc[2] = c4.z; cc[3] = c4.w;
            } else {
                const float4 c4 = *reinterpret_cast<const float4*>(CM + (size_t)irow * NN + lane * 4);
                cc[0] = c4.x; cc[1] = c4.y; cc[2] = c4.z; cc[3] = c4.w;
            }
        } else {
            if (irow < n) {
                #pragma unroll
                for (int r = 0; r < 4; ++r)
                    cc[r] = CB[(size_t)(lane * 4 + r) * NN + irow];
            } else {
                #pragma unroll
                for (int r = 0; r < 4; ++r) cc[r] = 0.0f;
            }
        }
    };

    // ---- prologue: stage leading rows into LDS ----
    if (USE_WS) {
        #pragma unroll 4
        for (int row = 0; row < rcache; ++row) {
            const int base = row * NN + lane * 4;
            *reinterpret_cast<float4*>(&ldsrows[base]) =
                *reinterpret_cast<const float4*>(CM + base);
        }
        __syncthreads();
    }

    for (int cur = 0; cur < NN; ++cur) {
        // ---- Dijkstra shortest augmenting path (value-exact vs reference) ----
        // sp: shortest-path costs (frozen once scanned, via scadd saturation)
        // mreg: masked sp (INFV where scanned) carried across iterations
        // scadd: 0 normal, INFV once column scanned (doubles as the SC flag)
        float sp[4]    = {INFV, INFV, INFV, INFV};
        float mreg[4]  = {INFV, INFV, INFV, INFV};
        float scadd[4] = {0.f, 0.f, 0.f, 0.f};
        int  path[4]   = {-1, -1, -1, -1};
        int   SRm = 0;                    // per-lane 4-bit visited-rows mask
        int   i      = cur;               // wave-uniform
        float minVal = 0.0f;              // wave-uniform
        int   sink   = -1;

        float cc[4];
        load_row(i, cc);                  // software-pipelined (reissued in shadow below)

        // terminates within NN iterations (each adds a col to SC and an unmatched
        // col always exists); guard turns bugs into wrong answers, never hangs.
        for (int guard = 0; guard <= NN && sink < 0; ++guard) {
            if (lane == (i >> 2)) SRm |= 1 << (i & 3);
            const float u_i = read4f(u, i);   // overlaps the in-flight row load

            // --- critical chain: cc -> rrm -> m -> reduce -> j -> nxt ---
            float rrm[4], m[4];
            #pragma unroll
            for (int r = 0; r < 4; ++r) {
                // exact reference op order: ((minVal + c) - u_i) - v_j
                const float rr = minVal + cc[r] - u_i - v[r];
                // rr + 1e30 == 1e30 exactly (|rr| << ulp(1e30)) => masked like ref.
                rrm[r] = rr + scadd[r];
                m[r]   = fminf(mreg[r], rrm[r]);    // masked sp after this iteration
            }
            const float lanem = fminf(fminf(m[0], m[1]), fminf(m[2], m[3]));
            minVal = wave_min64(lanem);

            // first column achieving minVal (== jnp.argmin): first lane, first r
            const unsigned long long bal = __ballot(lanem == minVal);
            const int fl = (bal == 0ull) ? 0 : (__ffsll((long long)bal) - 1);
            // r4c readlanes depend only on fl -> issue in parallel with cand chain
            const int rc0 = rl(r4c[0], fl), rc1 = rl(r4c[1], fl);
            const int rc2 = rl(r4c[2], fl), rc3 = rl(r4c[3], fl);
            int cand = 0;
            if (m[3] == minVal) cand = 3;
            if (m[2] == minVal) cand = 2;
            if (m[1] == minVal) cand = 1;
            if (m[0] == minVal) cand = 0;
            const int candf = rl(cand, fl);
            const int j = fl * 4 + candf;
            const int nlo = (candf & 1) ? rc1 : rc0;
            const int nhi = (candf & 1) ? rc3 : rc2;
            const int nxt = (candf & 2) ? nhi : nlo;

            const bool sinkp = (nxt < 0);
            const int i_next = sinkp ? i : nxt;
            load_row(i_next, cc);             // issue next row load NOW...

            // --- shadow work: independent of the in-flight load ---
            #pragma unroll
            for (int r = 0; r < 4; ++r) {
                const bool upd = rrm[r] < sp[r];     // strict <; false for scanned
                path[r] = upd ? i : path[r];
                sp[r]   = fminf(sp[r], rrm[r]);
                const bool isj = (lane == fl) && (r == candf);
                mreg[r]  = isj ? INFV : m[r];
                scadd[r] = isj ? INFV : scadd[r];
            }

            if (sinkp) sink = j;
            else       i = i_next;
        }

        // dump sp for the dual-update gather (only per-outer LDS use)
        *reinterpret_cast<float4*>(&sp_s[lane * 4]) = make_float4(sp[0], sp[1], sp[2], sp[3]);
        __syncthreads();

        // ---- dual updates (select semantics, same elementwise ops as reference) ----
        #pragma unroll
        for (int r = 0; r < 4; ++r) {
            const int row = lane * 4 + r;
            if ((SRm >> r) & 1) {
                float du;
                if (row == cur) {
                    du = minVal;
                } else {
                    int c = c4r[r];
                    c = c < 0 ? 0 : c;            // clip like reference
                    du = minVal - sp_s[c];
                }
                u[r] = u[r] + du;
            }
            if (scadd[r] != 0.0f) v[r] = v[r] - (minVal - sp[r]);   // scadd!=0 <=> SC
        }
        __syncthreads();

        // ---- augment along alternating path (wave-uniform walk, registers) ----
        {
            int j = sink;
            for (int guard = 0; guard < NN; ++guard) {
                const int ii = read4i(path, j);
                write4i(r4c, j, ii, lane);
                const int jn = read4i(c4r, ii);
                write4i(c4r, ii, j, lane);
                if (ii == cur) break;
                j = jn;
            }
        }
    }

    // ---- emit output ----
    int* ob = out + b * NN;
    #pragma unroll
    for (int r = 0; r < 4; ++r) {
        const int row = lane * 4 + r;
        if (row < n) ob[row] = c4r[r];
        tmp_s[lane * 4 + r] = r4c[r];
    }
    __syncthreads();
    if (lane == 0) {
        int cnt = 0;
        for (int c = 0; c < NN; ++c) {
            if (tmp_s[c] >= n) {      // column assigned to an invalid row => unused
                ob[n + cnt] = c;
                ++cnt;
            }
        }
    }
}

extern "C" void kernel_launch(void* const* d_in, const int* in_sizes, int n_in,
                              void* d_out, int out_size, void* d_ws, size_t ws_size,
                              hipStream_t stream) {
    const float* costs = (const float*)d_in[0];
    const void*  mask  = d_in[1];
    int*         out   = (int*)d_out;

    const int B = in_sizes[1] / NN;   // in_sizes[1] = B*N
    const size_t need = (size_t)B * NN * NN * sizeof(float);

    if (ws_size >= need && d_ws != nullptr) {
        float* ws = (float*)d_ws;
        transpose_mask_kernel<<<dim3(NN / 32, NN / 32, B), dim3(32, 8), 0, stream>>>(costs, mask, ws);

        // 158-row (158 KB) LDS row cache: 158*1024 + 2 KB static = 160 KB exactly.
        // hipFuncSetAttribute is host-side (graph-capture safe); fall back to 60
        // rows if rejected.
        int rcache = 158;
        hipError_t e = hipFuncSetAttribute(
            reinterpret_cast<const void*>(&lap_kernel<true>),
            hipFuncAttributeMaxDynamicSharedMemorySize,
            rcache * NN * (int)sizeof(float));
        if (e != hipSuccess) rcache = 60;
        const size_t dynbytes = (size_t)rcache * NN * sizeof(float);

        lap_kernel<true><<<dim3(B), dim3(64), dynbytes, stream>>>(costs, mask, ws, out, rcache);
    } else {
        lap_kernel<false><<<dim3(B), dim3(64), 0, stream>>>(costs, mask, nullptr, out, 0);
    }
}

// Round 7
// 6084.868 us; speedup vs baseline: 1.1813x; 1.0677x over previous
//
#include <hip/hip_runtime.h>

#define NN 256
#define INFV 1e30f

// ---- mask format handling (bool may arrive as bytes, int32, or float32) ----
__device__ __forceinline__ int mask_fmt(const void* m) {
    int w0 = ((const int*)m)[0];          // mask[0][0] is always true (lengths >= N/2)
    if (w0 == 1) return 0;                // int32 0/1
    if (w0 == 0x3F800000) return 1;       // float32 1.0f
    return 2;                             // 1-byte bool
}
__device__ __forceinline__ bool mask_at(const void* m, int fmt, int idx) {
    if (fmt == 0) return ((const int*)m)[idx] != 0;
    if (fmt == 1) return ((const float*)m)[idx] != 0.0f;
    return ((const unsigned char*)m)[idx] != 0;
}

// ---- tiled transpose + mask: ws[b][i][j] = mask[b][i] ? costs[b][j][i] : 0 ----
__global__ void transpose_mask_kernel(const float* __restrict__ costs,
                                      const void* __restrict__ mask,
                                      float* __restrict__ ws) {
    __shared__ float tile[32][33];
    const int b  = blockIdx.z;
    const int i0 = blockIdx.x * 32;
    const int j0 = blockIdx.y * 32;
    const int tx = threadIdx.x;   // 0..31
    const int ty = threadIdx.y;   // 0..7
    const int fmt = mask_fmt(mask);
    const float* Cb = costs + (size_t)b * NN * NN;
    float* Wb = ws + (size_t)b * NN * NN;

    #pragma unroll
    for (int k = 0; k < 32; k += 8) {
        tile[ty + k][tx] = Cb[(size_t)(j0 + ty + k) * NN + (i0 + tx)];
    }
    __syncthreads();
    #pragma unroll
    for (int k = 0; k < 32; k += 8) {
        const int i = i0 + ty + k;
        const int j = j0 + tx;
        const bool mv = mask_at(mask, fmt, b * NN + i);
        Wb[(size_t)i * NN + j] = mv ? tile[tx][ty + k] : 0.0f;
    }
}

// ---------- cross-lane helpers ----------
__device__ __forceinline__ int rl(int v, int lane) {
    return __builtin_amdgcn_readlane(v, lane);
}
__device__ __forceinline__ float rlf(float v, int lane) {
    return __int_as_float(__builtin_amdgcn_readlane(__float_as_int(v), lane));
}
// read element idx (uniform, 0..255) from a distributed array: lane k holds elems 4k..4k+3
__device__ __forceinline__ int read4i(const int a[4], int idx) {
    const int lane = idx >> 2;
    const int v0 = rl(a[0], lane), v1 = rl(a[1], lane);
    const int v2 = rl(a[2], lane), v3 = rl(a[3], lane);
    const int lo = (idx & 1) ? v1 : v0;
    const int hi = (idx & 1) ? v3 : v2;
    return (idx & 2) ? hi : lo;
}
__device__ __forceinline__ float read4f(const float a[4], int idx) {
    const int lane = idx >> 2;
    const int v0 = rl(__float_as_int(a[0]), lane), v1 = rl(__float_as_int(a[1]), lane);
    const int v2 = rl(__float_as_int(a[2]), lane), v3 = rl(__float_as_int(a[3]), lane);
    const int lo = (idx & 1) ? v1 : v0;
    const int hi = (idx & 1) ? v3 : v2;
    return __int_as_float((idx & 2) ? hi : lo);
}
// write val to distributed array element idx (idx uniform)
__device__ __forceinline__ void write4i(int (&a)[4], int idx, int val, int lane) {
    if (lane == (idx >> 2)) {
        switch (idx & 3) {
            case 0: a[0] = val; break;
            case 1: a[1] = val; break;
            case 2: a[2] = val; break;
            default: a[3] = val; break;
        }
    }
}

// DPP move: result = src from DPP-selected lane; lanes with no valid source keep old(=x)
template <int CTRL>
__device__ __forceinline__ float dpp_mov_f(float x) {
    return __int_as_float(__builtin_amdgcn_update_dpp(
        __float_as_int(x), __float_as_int(x), CTRL, 0xf, 0xf, false));
}
// full-wave min: row_shr 1,2,4,8 accumulates toward lane 15/31/47/63 of each 16-row;
// row_bcast:15 merges row pairs, row_bcast:31 merges halves (lane 63 <- global min).
__device__ __forceinline__ float wave_min64(float x) {
    x = fminf(x, dpp_mov_f<0x111>(x));  // row_shr:1
    x = fminf(x, dpp_mov_f<0x112>(x));  // row_shr:2
    x = fminf(x, dpp_mov_f<0x114>(x));  // row_shr:4
    x = fminf(x, dpp_mov_f<0x118>(x));  // row_shr:8
    x = fminf(x, dpp_mov_f<0x142>(x));  // row_bcast:15
    x = fminf(x, dpp_mov_f<0x143>(x));  // row_bcast:31
    return rlf(x, 63);
}

// ---- exact JV LAP, one block (1 wave, 64 lanes) per batch, 4 cols/lane ----
// rcache = leading rows of the (transposed+masked) cost matrix held in dynamic LDS.
template <bool USE_WS>
__global__ __launch_bounds__(64)
void lap_kernel(const float* __restrict__ costs,
                const void* __restrict__ mask,
                const float* __restrict__ cmat,
                int* __restrict__ out,
                int rcache) {
    extern __shared__ float ldsrows[];   // [rcache][NN]

    const int b    = blockIdx.x;
    const int lane = threadIdx.x;   // lane owns rows/cols lane*4 .. lane*4+3

    __shared__ float sp_s[NN];
    __shared__ int   tmp_s[NN];

    const int fmt = mask_fmt(mask);

    // n = count of valid objects (mask is prefix-true)
    int nloc = 0;
    #pragma unroll
    for (int r = 0; r < 4; ++r)
        nloc += mask_at(mask, fmt, b * NN + lane * 4 + r) ? 1 : 0;
    #pragma unroll
    for (int off = 32; off; off >>= 1) nloc += __shfl_xor(nloc, off);
    const int n  = nloc;
    const int ns = __builtin_amdgcn_readfirstlane(n);   // SGPR copy -> scalar branches

    // distributed state (registers): lane k holds element 4k+r
    float u[4]  = {0.f, 0.f, 0.f, 0.f};   // row potentials
    float v[4]  = {0.f, 0.f, 0.f, 0.f};   // col potentials
    int  c4r[4] = {-1, -1, -1, -1};       // col4row (by row)
    int  r4c[4] = {-1, -1, -1, -1};       // row4col (by col)

    const float* CM = cmat + (size_t)b * NN * NN;   // transposed+masked
    const float* CB = costs + (size_t)b * NN * NN;  // raw (fallback)

    // row loader; irow is ALWAYS a wave-uniform SGPR value here, so all three
    // branches are scalar (s_cmp + s_cbranch). Rows >= ns are exactly zero in CM.
    auto load_row = [&](int irow, float (&cc)[4]) {
        if (USE_WS) {
            if (irow >= ns) {
                cc[0] = cc[1] = cc[2] = cc[3] = 0.0f;
            } else if (irow < rcache) {
                const float4 c4 = *reinterpret_cast<const float4*>(&ldsrows[irow * NN + lane * 4]);
                cc[0] = c4.x; cc[1] = c4.y; cc[2] = c4.z; cc[3] = c4.w;
            } else {
                const float4 c4 = *reinterpret_cast<const float4*>(CM + (size_t)irow * NN + lane * 4);
                cc[0] = c4.x; cc[1] = c4.y; cc[2] = c4.z; cc[3] = c4.w;
            }
        } else {
            if (irow < ns) {
                #pragma unroll
                for (int r = 0; r < 4; ++r)
                    cc[r] = CB[(size_t)(lane * 4 + r) * NN + irow];
            } else {
                #pragma unroll
                for (int r = 0; r < 4; ++r) cc[r] = 0.0f;
            }
        }
    };

    // ---- prologue: stage leading rows into LDS ----
    if (USE_WS) {
        #pragma unroll 4
        for (int row = 0; row < rcache; ++row) {
            const int base = row * NN + lane * 4;
            *reinterpret_cast<float4*>(&ldsrows[base]) =
                *reinterpret_cast<const float4*>(CM + base);
        }
        __syncthreads();
    }

    for (int cur = 0; cur < NN; ++cur) {
        // ---- Dijkstra shortest augmenting path (value-exact vs reference) ----
        // sp: shortest-path costs; mreg: masked sp (INFV once scanned), carried;
        // scadd: 0 normal / INFV once scanned (the SC flag); mregmin: min(mreg).
        float sp[4]    = {INFV, INFV, INFV, INFV};
        float mreg[4]  = {INFV, INFV, INFV, INFV};
        float scadd[4] = {0.f, 0.f, 0.f, 0.f};
        float mregmin  = INFV;
        int  path[4]   = {-1, -1, -1, -1};
        int   SRm = 0;                    // per-lane 4-bit visited-rows mask
        int   i      = cur;               // wave-uniform (SGPR)
        float minVal = 0.0f;              // wave-uniform
        int   sink   = -1;

        float cc[4];
        load_row(i, cc);                  // software-pipelined (reissued at loop bottom)

        // terminates within NN iterations (each adds a col to SC and an unmatched
        // col always exists); guard turns bugs into wrong answers, never hangs.
        for (int guard = 0; guard <= NN && sink < 0; ++guard) {
            if (lane == (i >> 2)) SRm |= 1 << (i & 3);
            const float u_i = read4f(u, i);   // scalar selects; hides under load

            // --- critical chain: cc -> rrm -> lanem -> reduce -> ballot -> nxt ---
            float rrm[4];
            #pragma unroll
            for (int r = 0; r < 4; ++r) {
                // exact reference op order: ((minVal + c) - u_i) - v_j
                const float rr = minVal + cc[r] - u_i - v[r];
                // rr + 1e30 == 1e30 exactly (|rr| << ulp(1e30)) => masked like ref.
                rrm[r] = rr + scadd[r];
            }
            const float lanem = fminf(fminf(fminf(rrm[0], rrm[1]), rrm[2]),
                                      fminf(rrm[3], mregmin));
            minVal = wave_min64(lanem);

            // --- speculation (parallel with the reduce): this lane's first-index
            // candidate and its r4c value; valid iff this lane wins the ballot.
            float m[4];
            #pragma unroll
            for (int r = 0; r < 4; ++r) m[r] = fminf(mreg[r], rrm[r]);
            int candr = 3;
            if (m[2] == lanem) candr = 2;
            if (m[1] == lanem) candr = 1;
            if (m[0] == lanem) candr = 0;
            const int cn01 = (candr & 1) ? r4c[1] : r4c[0];
            const int cn23 = (candr & 1) ? r4c[3] : r4c[2];
            const int candnxt = (candr & 2) ? cn23 : cn01;

            // --- post-reduce: first lane achieving minVal (== jnp.argmin) ---
            const unsigned long long bal = __ballot(lanem == minVal);
            const int fl  = (bal == 0ull) ? 0 : (__ffsll((long long)bal) - 1);
            const int jr  = rl(candr, fl);
            const int nxt = rl(candnxt, fl);
            const int j   = fl * 4 + jr;

            const bool sinkp  = (nxt < 0);
            const int  i_next = __builtin_amdgcn_readfirstlane(sinkp ? i : nxt);
            load_row(i_next, cc);             // issue next row load NOW (scalar branches)

            // --- shadow work (hidden under the in-flight load) ---
            #pragma unroll
            for (int r = 0; r < 4; ++r) {
                const bool upd = rrm[r] < sp[r];     // strict <; false once scanned
                path[r] = upd ? i : path[r];
                sp[r]   = fminf(sp[r], rrm[r]);
                const bool isj = (lane == fl) && (r == jr);
                mreg[r]  = isj ? INFV : m[r];
                scadd[r] = isj ? INFV : scadd[r];
            }
            mregmin = fminf(fminf(mreg[0], mreg[1]), fminf(mreg[2], mreg[3]));

            if (sinkp) sink = j;
            else       i = i_next;
        }

        // dump sp for the dual-update gather (only per-outer LDS use)
        *reinterpret_cast<float4*>(&sp_s[lane * 4]) = make_float4(sp[0], sp[1], sp[2], sp[3]);
        __syncthreads();

        // ---- dual updates (select semantics, same elementwise ops as reference) ----
        #pragma unroll
        for (int r = 0; r < 4; ++r) {
            const int row = lane * 4 + r;
            if ((SRm >> r) & 1) {
                float du;
                if (row == cur) {
                    du = minVal;
                } else {
                    int c = c4r[r];
                    c = c < 0 ? 0 : c;            // clip like reference
                    du = minVal - sp_s[c];
                }
                u[r] = u[r] + du;
            }
            if (scadd[r] != 0.0f) v[r] = v[r] - (minVal - sp[r]);   // scadd!=0 <=> SC
        }
        __syncthreads();

        // ---- augment along alternating path (wave-uniform walk, registers) ----
        {
            int j = sink;
            for (int guard = 0; guard < NN; ++guard) {
                const int ii = read4i(path, j);
                write4i(r4c, j, ii, lane);
                const int jn = read4i(c4r, ii);
                write4i(c4r, ii, j, lane);
                if (ii == cur) break;
                j = jn;
            }
        }
    }

    // ---- emit output ----
    int* ob = out + b * NN;
    #pragma unroll
    for (int r = 0; r < 4; ++r) {
        const int row = lane * 4 + r;
        if (row < n) ob[row] = c4r[r];
        tmp_s[lane * 4 + r] = r4c[r];
    }
    __syncthreads();
    if (lane == 0) {
        int cnt = 0;
        for (int c = 0; c < NN; ++c) {
            if (tmp_s[c] >= n) {      // column assigned to an invalid row => unused
                ob[n + cnt] = c;
                ++cnt;
            }
        }
    }
}

extern "C" void kernel_launch(void* const* d_in, const int* in_sizes, int n_in,
                              void* d_out, int out_size, void* d_ws, size_t ws_size,
                              hipStream_t stream) {
    const float* costs = (const float*)d_in[0];
    const void*  mask  = d_in[1];
    int*         out   = (int*)d_out;

    const int B = in_sizes[1] / NN;   // in_sizes[1] = B*N
    const size_t need = (size_t)B * NN * NN * sizeof(float);

    if (ws_size >= need && d_ws != nullptr) {
        float* ws = (float*)d_ws;
        transpose_mask_kernel<<<dim3(NN / 32, NN / 32, B), dim3(32, 8), 0, stream>>>(costs, mask, ws);

        // 158-row (158 KB) LDS row cache: 158*1024 + 2 KB static = 160 KB exactly.
        // hipFuncSetAttribute is host-side (graph-capture safe); fall back to 60
        // rows if rejected.
        int rcache = 158;
        hipError_t e = hipFuncSetAttribute(
            reinterpret_cast<const void*>(&lap_kernel<true>),
            hipFuncAttributeMaxDynamicSharedMemorySize,
            rcache * NN * (int)sizeof(float));
        if (e != hipSuccess) rcache = 60;
        const size_t dynbytes = (size_t)rcache * NN * sizeof(float);

        lap_kernel<true><<<dim3(B), dim3(64), dynbytes, stream>>>(costs, mask, ws, out, rcache);
    } else {
        lap_kernel<false><<<dim3(B), dim3(64), 0, stream>>>(costs, mask, nullptr, out, 0);
    }
}

// Round 8
// 5358.765 us; speedup vs baseline: 1.3414x; 1.1355x over previous
//
#include <hip/hip_runtime.h>

#define NN 256
#define INFV 1e30f

// ---- mask format handling (bool may arrive as bytes, int32, or float32) ----
__device__ __forceinline__ int mask_fmt(const void* m) {
    int w0 = ((const int*)m)[0];          // mask[0][0] is always true (lengths >= N/2)
    if (w0 == 1) return 0;                // int32 0/1
    if (w0 == 0x3F800000) return 1;       // float32 1.0f
    return 2;                             // 1-byte bool
}
__device__ __forceinline__ bool mask_at(const void* m, int fmt, int idx) {
    if (fmt == 0) return ((const int*)m)[idx] != 0;
    if (fmt == 1) return ((const float*)m)[idx] != 0.0f;
    return ((const unsigned char*)m)[idx] != 0;
}

// ---- tiled transpose + mask: ws[b][i][j] = mask[b][i] ? costs[b][j][i] : 0 ----
__global__ void transpose_mask_kernel(const float* __restrict__ costs,
                                      const void* __restrict__ mask,
                                      float* __restrict__ ws) {
    __shared__ float tile[32][33];
    const int b  = blockIdx.z;
    const int i0 = blockIdx.x * 32;
    const int j0 = blockIdx.y * 32;
    const int tx = threadIdx.x;   // 0..31
    const int ty = threadIdx.y;   // 0..7
    const int fmt = mask_fmt(mask);
    const float* Cb = costs + (size_t)b * NN * NN;
    float* Wb = ws + (size_t)b * NN * NN;

    #pragma unroll
    for (int k = 0; k < 32; k += 8) {
        tile[ty + k][tx] = Cb[(size_t)(j0 + ty + k) * NN + (i0 + tx)];
    }
    __syncthreads();
    #pragma unroll
    for (int k = 0; k < 32; k += 8) {
        const int i = i0 + ty + k;
        const int j = j0 + tx;
        const bool mv = mask_at(mask, fmt, b * NN + i);
        Wb[(size_t)i * NN + j] = mv ? tile[tx][ty + k] : 0.0f;
    }
}

// ---------- cross-lane helpers ----------
__device__ __forceinline__ int rl(int v, int lane) {
    return __builtin_amdgcn_readlane(v, lane);
}
__device__ __forceinline__ float rlf(float v, int lane) {
    return __int_as_float(__builtin_amdgcn_readlane(__float_as_int(v), lane));
}
// read element idx (uniform, 0..255) from a distributed array: lane k holds elems 4k..4k+3
__device__ __forceinline__ int read4i(const int a[4], int idx) {
    const int lane = idx >> 2;
    const int v0 = rl(a[0], lane), v1 = rl(a[1], lane);
    const int v2 = rl(a[2], lane), v3 = rl(a[3], lane);
    const int lo = (idx & 1) ? v1 : v0;
    const int hi = (idx & 1) ? v3 : v2;
    return (idx & 2) ? hi : lo;
}
__device__ __forceinline__ float read4f(const float a[4], int idx) {
    const int lane = idx >> 2;
    const int v0 = rl(__float_as_int(a[0]), lane), v1 = rl(__float_as_int(a[1]), lane);
    const int v2 = rl(__float_as_int(a[2]), lane), v3 = rl(__float_as_int(a[3]), lane);
    const int lo = (idx & 1) ? v1 : v0;
    const int hi = (idx & 1) ? v3 : v2;
    return __int_as_float((idx & 2) ? hi : lo);
}
// write val to distributed array element idx (idx uniform)
__device__ __forceinline__ void write4i(int (&a)[4], int idx, int val, int lane) {
    if (lane == (idx >> 2)) {
        switch (idx & 3) {
            case 0: a[0] = val; break;
            case 1: a[1] = val; break;
            case 2: a[2] = val; break;
            default: a[3] = val; break;
        }
    }
}

// DPP move: result = src from DPP-selected lane; lanes with no valid source keep old(=x)
template <int CTRL>
__device__ __forceinline__ float dpp_mov_f(float x) {
    return __int_as_float(__builtin_amdgcn_update_dpp(
        __float_as_int(x), __float_as_int(x), CTRL, 0xf, 0xf, false));
}
// full-wave min: row_shr 1,2,4,8 accumulates toward lane 15/31/47/63 of each 16-row;
// row_bcast:15 merges row pairs, row_bcast:31 merges halves (lane 63 <- global min).
__device__ __forceinline__ float wave_min64(float x) {
    x = fminf(x, dpp_mov_f<0x111>(x));  // row_shr:1
    x = fminf(x, dpp_mov_f<0x112>(x));  // row_shr:2
    x = fminf(x, dpp_mov_f<0x114>(x));  // row_shr:4
    x = fminf(x, dpp_mov_f<0x118>(x));  // row_shr:8
    x = fminf(x, dpp_mov_f<0x142>(x));  // row_bcast:15
    x = fminf(x, dpp_mov_f<0x143>(x));  // row_bcast:31
    return rlf(x, 63);
}

// ---- exact JV LAP, one block (1 wave, 64 lanes) per batch, 4 cols/lane ----
// rcache = number of leading rows of the (transposed+masked) cost matrix held in
// dynamic LDS (populated in the prologue). 0 disables the cache.
template <bool USE_WS>
__global__ __launch_bounds__(64)
void lap_kernel(const float* __restrict__ costs,
                const void* __restrict__ mask,
                const float* __restrict__ cmat,
                int* __restrict__ out,
                int rcache) {
    extern __shared__ float ldsrows[];   // [rcache][NN]

    const int b    = blockIdx.x;
    const int lane = threadIdx.x;   // lane owns rows/cols lane*4 .. lane*4+3

    __shared__ float sp_s[NN];
    __shared__ int   tmp_s[NN];

    const int fmt = mask_fmt(mask);

    // n = count of valid objects (mask is prefix-true)
    int nloc = 0;
    #pragma unroll
    for (int r = 0; r < 4; ++r)
        nloc += mask_at(mask, fmt, b * NN + lane * 4 + r) ? 1 : 0;
    #pragma unroll
    for (int off = 32; off; off >>= 1) nloc += __shfl_xor(nloc, off);
    const int n = nloc;

    // distributed state (registers): lane k holds element 4k+r
    float u[4]  = {0.f, 0.f, 0.f, 0.f};   // row potentials
    float v[4]  = {0.f, 0.f, 0.f, 0.f};   // col potentials
    int  c4r[4] = {-1, -1, -1, -1};       // col4row (by row)
    int  r4c[4] = {-1, -1, -1, -1};       // row4col (by col)

    const float* CM = cmat + (size_t)b * NN * NN;   // transposed+masked
    const float* CB = costs + (size_t)b * NN * NN;  // raw (fallback)

    // ---- prologue: stage leading rows into LDS (one row per iteration) ----
    if (USE_WS) {
        #pragma unroll 4
        for (int row = 0; row < rcache; ++row) {
            const int base = row * NN + lane * 4;
            *reinterpret_cast<float4*>(&ldsrows[base]) =
                *reinterpret_cast<const float4*>(CM + base);
        }
        __syncthreads();
    }

    for (int cur = 0; cur < NN; ++cur) {
        // ---- Dijkstra shortest augmenting path (bit-exact vs reference) ----
        float sp[4]  = {INFV, INFV, INFV, INFV};
        int  path[4] = {-1, -1, -1, -1};
        int   SCm = 0, SRm = 0;           // per-lane 4-bit masks
        int   i      = cur;               // wave-uniform
        float minVal = 0.0f;              // wave-uniform
        int   sink   = -1;

        // terminates within NN iterations (each adds a col to SC and an
        // unmatched col always exists); guard turns bugs into wrong answers,
        // never hangs.
        for (int guard = 0; guard <= NN && sink < 0; ++guard) {
            if (lane == (i >> 2)) SRm |= 1 << (i & 3);

            float cc[4];
            if (USE_WS) {
                if (i < rcache) {   // wave-uniform branch (i is readlane'd)
                    const float4 c4 = *reinterpret_cast<const float4*>(&ldsrows[i * NN + lane * 4]);
                    cc[0] = c4.x; cc[1] = c4.y; cc[2] = c4.z; cc[3] = c4.w;
                } else {
                    const float4 c4 = *reinterpret_cast<const float4*>(CM + (size_t)i * NN + lane * 4);
                    cc[0] = c4.x; cc[1] = c4.y; cc[2] = c4.z; cc[3] = c4.w;
                }
            } else {
                if (i < n) {
                    #pragma unroll
                    for (int r = 0; r < 4; ++r)
                        cc[r] = CB[(size_t)(lane * 4 + r) * NN + i];
                } else {
                    #pragma unroll
                    for (int r = 0; r < 4; ++r) cc[r] = 0.0f;
                }
            }
            const float u_i = read4f(u, i);   // uniform scalar

            float m[4];
            #pragma unroll
            for (int r = 0; r < 4; ++r) {
                // exact reference op order: ((minVal + c) - u_i) - v_j
                const float rr = minVal + cc[r] - u_i - v[r];
                const bool sc = (SCm >> r) & 1;
                if (!sc && rr < sp[r]) { sp[r] = rr; path[r] = i; }
                m[r] = sc ? INFV : sp[r];
            }

            // wave-wide min of m (value), broadcast to all lanes
            const float bestv = fminf(fminf(m[0], m[1]), fminf(m[2], m[3]));
            minVal = wave_min64(bestv);

            // --- speculation, runs in parallel with the DPP reduce chain: this
            // lane's first-index candidate and its r4c value; both valid exactly
            // for the lane that wins the ballot below.
            int candr = 3;
            if (m[2] == bestv) candr = 2;
            if (m[1] == bestv) candr = 1;
            if (m[0] == bestv) candr = 0;
            const int cn01 = (candr & 1) ? r4c[1] : r4c[0];
            const int cn23 = (candr & 1) ? r4c[3] : r4c[2];
            const int candnxt = (candr & 2) ? cn23 : cn01;

            // --- post-reduce: first lane achieving minVal, then its first r
            // (lowest global column index == jnp.argmin tie-break).
            const unsigned long long bal = __ballot(bestv == minVal);
            const int fl  = (bal == 0ull) ? 0 : (__ffsll((long long)bal) - 1);
            const int jr  = rl(candr, fl);
            const int nxt = rl(candnxt, fl);
            const int j   = fl * 4 + jr;

            if (lane == fl) SCm |= 1 << jr;
            if (nxt < 0) sink = j;
            else         i = nxt;
        }

        // dump sp for the dual-update gather (only per-outer LDS use)
        *reinterpret_cast<float4*>(&sp_s[lane * 4]) = make_float4(sp[0], sp[1], sp[2], sp[3]);
        __syncthreads();

        // ---- dual updates (select semantics, same elementwise ops as reference) ----
        #pragma unroll
        for (int r = 0; r < 4; ++r) {
            const int row = lane * 4 + r;
            if ((SRm >> r) & 1) {
                float du;
                if (row == cur) {
                    du = minVal;
                } else {
                    int c = c4r[r];
                    c = c < 0 ? 0 : c;            // clip like reference
                    du = minVal - sp_s[c];
                }
                u[r] = u[r] + du;
            }
            if ((SCm >> r) & 1) v[r] = v[r] - (minVal - sp[r]);
        }
        __syncthreads();

        // ---- augment along alternating path (wave-uniform walk, registers) ----
        {
            int j = sink;
            for (int guard = 0; guard < NN; ++guard) {
                const int ii = read4i(path, j);
                write4i(r4c, j, ii, lane);
                const int jn = read4i(c4r, ii);
                write4i(c4r, ii, j, lane);
                if (ii == cur) break;
                j = jn;
            }
        }
    }

    // ---- emit output ----
    int* ob = out + b * NN;
    #pragma unroll
    for (int r = 0; r < 4; ++r) {
        const int row = lane * 4 + r;
        if (row < n) ob[row] = c4r[r];
        tmp_s[lane * 4 + r] = r4c[r];
    }
    __syncthreads();
    if (lane == 0) {
        int cnt = 0;
        for (int c = 0; c < NN; ++c) {
            if (tmp_s[c] >= n) {      // column assigned to an invalid row => unused
                ob[n + cnt] = c;
                ++cnt;
            }
        }
    }
}

extern "C" void kernel_launch(void* const* d_in, const int* in_sizes, int n_in,
                              void* d_out, int out_size, void* d_ws, size_t ws_size,
                              hipStream_t stream) {
    const float* costs = (const float*)d_in[0];
    const void*  mask  = d_in[1];
    int*         out   = (int*)d_out;

    const int B = in_sizes[1] / NN;   // in_sizes[1] = B*N
    const size_t need = (size_t)B * NN * NN * sizeof(float);

    if (ws_size >= need && d_ws != nullptr) {
        float* ws = (float*)d_ws;
        transpose_mask_kernel<<<dim3(NN / 32, NN / 32, B), dim3(32, 8), 0, stream>>>(costs, mask, ws);

        // 158-row (158 KB) LDS row cache: 158*1024 + 2 KB static = 160 KB exactly.
        // hipFuncSetAttribute is host-side (graph-capture safe); fall back to 60
        // rows if rejected.
        int rcache = 158;
        hipError_t e = hipFuncSetAttribute(
            reinterpret_cast<const void*>(&lap_kernel<true>),
            hipFuncAttributeMaxDynamicSharedMemorySize,
            rcache * NN * (int)sizeof(float));
        if (e != hipSuccess) rcache = 60;
        const size_t dynbytes = (size_t)rcache * NN * sizeof(float);

        lap_kernel<true><<<dim3(B), dim3(64), dynbytes, stream>>>(costs, mask, ws, out, rcache);
    } else {
        lap_kernel<false><<<dim3(B), dim3(64), 0, stream>>>(costs, mask, nullptr, out, 0);
    }
}

// Round 9
// 4820.613 us; speedup vs baseline: 1.4911x; 1.1116x over previous
//
#include <hip/hip_runtime.h>

#define NN 256
#define INFV 1e30f

// ---- mask format handling (bool may arrive as bytes, int32, or float32) ----
__device__ __forceinline__ int mask_fmt(const void* m) {
    int w0 = ((const int*)m)[0];          // mask[0][0] is always true (lengths >= N/2)
    if (w0 == 1) return 0;                // int32 0/1
    if (w0 == 0x3F800000) return 1;       // float32 1.0f
    return 2;                             // 1-byte bool
}
__device__ __forceinline__ bool mask_at(const void* m, int fmt, int idx) {
    if (fmt == 0) return ((const int*)m)[idx] != 0;
    if (fmt == 1) return ((const float*)m)[idx] != 0.0f;
    return ((const unsigned char*)m)[idx] != 0;
}

// ---- tiled transpose + mask: ws[b][i][j] = mask[b][i] ? costs[b][j][i] : 0 ----
__global__ void transpose_mask_kernel(const float* __restrict__ costs,
                                      const void* __restrict__ mask,
                                      float* __restrict__ ws) {
    __shared__ float tile[32][33];
    const int b  = blockIdx.z;
    const int i0 = blockIdx.x * 32;
    const int j0 = blockIdx.y * 32;
    const int tx = threadIdx.x;   // 0..31
    const int ty = threadIdx.y;   // 0..7
    const int fmt = mask_fmt(mask);
    const float* Cb = costs + (size_t)b * NN * NN;
    float* Wb = ws + (size_t)b * NN * NN;

    #pragma unroll
    for (int k = 0; k < 32; k += 8) {
        tile[ty + k][tx] = Cb[(size_t)(j0 + ty + k) * NN + (i0 + tx)];
    }
    __syncthreads();
    #pragma unroll
    for (int k = 0; k < 32; k += 8) {
        const int i = i0 + ty + k;
        const int j = j0 + tx;
        const bool mv = mask_at(mask, fmt, b * NN + i);
        Wb[(size_t)i * NN + j] = mv ? tile[tx][ty + k] : 0.0f;
    }
}

// ---------- cross-lane helpers ----------
__device__ __forceinline__ int rl(int v, int lane) {
    return __builtin_amdgcn_readlane(v, lane);
}
__device__ __forceinline__ float rlf(float v, int lane) {
    return __int_as_float(__builtin_amdgcn_readlane(__float_as_int(v), lane));
}
// read element idx (uniform, 0..255) from a distributed array: lane k holds elems 4k..4k+3
__device__ __forceinline__ int read4i(const int a[4], int idx) {
    const int lane = idx >> 2;
    const int v0 = rl(a[0], lane), v1 = rl(a[1], lane);
    const int v2 = rl(a[2], lane), v3 = rl(a[3], lane);
    const int lo = (idx & 1) ? v1 : v0;
    const int hi = (idx & 1) ? v3 : v2;
    return (idx & 2) ? hi : lo;
}
__device__ __forceinline__ float read4f(const float a[4], int idx) {
    const int lane = idx >> 2;
    const int v0 = rl(__float_as_int(a[0]), lane), v1 = rl(__float_as_int(a[1]), lane);
    const int v2 = rl(__float_as_int(a[2]), lane), v3 = rl(__float_as_int(a[3]), lane);
    const int lo = (idx & 1) ? v1 : v0;
    const int hi = (idx & 1) ? v3 : v2;
    return __int_as_float((idx & 2) ? hi : lo);
}
// write val to distributed array element idx (idx uniform)
__device__ __forceinline__ void write4i(int (&a)[4], int idx, int val, int lane) {
    if (lane == (idx >> 2)) {
        switch (idx & 3) {
            case 0: a[0] = val; break;
            case 1: a[1] = val; break;
            case 2: a[2] = val; break;
            default: a[3] = val; break;
        }
    }
}

// DPP move: result = src from DPP-selected lane; lanes with no valid source keep old(=x)
template <int CTRL>
__device__ __forceinline__ float dpp_mov_f(float x) {
    return __int_as_float(__builtin_amdgcn_update_dpp(
        __float_as_int(x), __float_as_int(x), CTRL, 0xf, 0xf, false));
}
// full-wave min: row_shr 1,2,4,8 accumulates toward lane 15/31/47/63 of each 16-row;
// row_bcast:15 merges row pairs, row_bcast:31 merges halves (lane 63 <- global min).
__device__ __forceinline__ float wave_min64(float x) {
    x = fminf(x, dpp_mov_f<0x111>(x));  // row_shr:1
    x = fminf(x, dpp_mov_f<0x112>(x));  // row_shr:2
    x = fminf(x, dpp_mov_f<0x114>(x));  // row_shr:4
    x = fminf(x, dpp_mov_f<0x118>(x));  // row_shr:8
    x = fminf(x, dpp_mov_f<0x142>(x));  // row_bcast:15
    x = fminf(x, dpp_mov_f<0x143>(x));  // row_bcast:31
    return rlf(x, 63);
}

// ---- exact JV LAP, one block (1 wave, 64 lanes) per batch, 4 cols/lane ----
// rcache = number of leading rows of the (transposed+masked) cost matrix held in
// dynamic LDS (populated in the prologue). 0 disables the cache.
template <bool USE_WS>
__global__ __launch_bounds__(64)
void lap_kernel(const float* __restrict__ costs,
                const void* __restrict__ mask,
                const float* __restrict__ cmat,
                int* __restrict__ out,
                int rcache) {
    extern __shared__ float ldsrows[];   // [rcache][NN]

    const int b    = blockIdx.x;
    const int lane = threadIdx.x;   // lane owns rows/cols lane*4 .. lane*4+3

    __shared__ float sp_s[NN];
    __shared__ int   tmp_s[NN];

    const int fmt = mask_fmt(mask);

    // n = count of valid objects (mask is prefix-true)
    int nloc = 0;
    #pragma unroll
    for (int r = 0; r < 4; ++r)
        nloc += mask_at(mask, fmt, b * NN + lane * 4 + r) ? 1 : 0;
    #pragma unroll
    for (int off = 32; off; off >>= 1) nloc += __shfl_xor(nloc, off);
    const int n = nloc;

    // distributed state (registers): lane k holds element 4k+r
    float u[4]  = {0.f, 0.f, 0.f, 0.f};   // row potentials
    float v[4]  = {0.f, 0.f, 0.f, 0.f};   // col potentials
    int  c4r[4] = {-1, -1, -1, -1};       // col4row (by row)
    int  r4c[4] = {-1, -1, -1, -1};       // row4col (by col)

    const float* CM = cmat + (size_t)b * NN * NN;   // transposed+masked
    const float* CB = costs + (size_t)b * NN * NN;  // raw (fallback)

    // ---- prologue: stage leading rows into LDS (one row per iteration) ----
    if (USE_WS) {
        #pragma unroll 4
        for (int row = 0; row < rcache; ++row) {
            const int base = row * NN + lane * 4;
            *reinterpret_cast<float4*>(&ldsrows[base]) =
                *reinterpret_cast<const float4*>(CM + base);
        }
        __syncthreads();
    }

    for (int cur = 0; cur < NN; ++cur) {
        // ---- Dijkstra shortest augmenting path (value-exact vs reference) ----
        // scadd: 0 normal / 1e30 once the column is scanned (the SC flag).
        //   rrm = rr + scadd: scanned -> exactly 1e30 (|rr| << ulp(1e30))
        //   sp  = fmin(sp, rrm): scanned cols stay frozen (== reference no-update)
        //   m   = sp + scadd: scanned -> exactly 1e30 (== reference INF), else sp
        float sp[4]    = {INFV, INFV, INFV, INFV};
        float scadd[4] = {0.f, 0.f, 0.f, 0.f};
        int  path[4]   = {-1, -1, -1, -1};
        int   SRm = 0;                    // per-lane 4-bit visited-rows mask
        int   i      = cur;               // wave-uniform
        float minVal = 0.0f;              // wave-uniform
        int   sink   = -1;

        // terminates within NN iterations (each adds a col to SC and an
        // unmatched col always exists); guard turns bugs into wrong answers,
        // never hangs.
        for (int guard = 0; guard <= NN && sink < 0; ++guard) {
            if (lane == (i >> 2)) SRm |= 1 << (i & 3);

            float cc[4];
            if (USE_WS) {
                if (i < rcache) {   // wave-uniform branch (i is readlane'd)
                    const float4 c4 = *reinterpret_cast<const float4*>(&ldsrows[i * NN + lane * 4]);
                    cc[0] = c4.x; cc[1] = c4.y; cc[2] = c4.z; cc[3] = c4.w;
                } else {
                    const float4 c4 = *reinterpret_cast<const float4*>(CM + (size_t)i * NN + lane * 4);
                    cc[0] = c4.x; cc[1] = c4.y; cc[2] = c4.z; cc[3] = c4.w;
                }
            } else {
                if (i < n) {
                    #pragma unroll
                    for (int r = 0; r < 4; ++r)
                        cc[r] = CB[(size_t)(lane * 4 + r) * NN + i];
                } else {
                    #pragma unroll
                    for (int r = 0; r < 4; ++r) cc[r] = 0.0f;
                }
            }
            const float u_i = read4f(u, i);   // uniform scalar; hides under load

            float m[4];
            #pragma unroll
            for (int r = 0; r < 4; ++r) {
                // exact reference op order: ((minVal + c) - u_i) - v_j
                const float rr  = minVal + cc[r] - u_i - v[r];
                const float rrm = rr + scadd[r];          // INF-masked like reference
                const bool upd = rrm < sp[r];             // strict <; false once scanned
                path[r] = upd ? i : path[r];
                sp[r]   = fminf(sp[r], rrm);              // frozen once scanned
                m[r]    = sp[r] + scadd[r];               // masked sp (1e30 if scanned)
            }

            // wave-wide min of m (value), broadcast to all lanes
            const float bestv = fminf(fminf(fminf(m[0], m[1]), m[2]), m[3]);
            minVal = wave_min64(bestv);

            // --- speculation, runs in parallel with the DPP reduce chain: this
            // lane's first-index candidate and its r4c value; both valid exactly
            // for the lane that wins the ballot below.
            int candr = 3;
            if (m[2] == bestv) candr = 2;
            if (m[1] == bestv) candr = 1;
            if (m[0] == bestv) candr = 0;
            const int cn01 = (candr & 1) ? r4c[1] : r4c[0];
            const int cn23 = (candr & 1) ? r4c[3] : r4c[2];
            const int candnxt = (candr & 2) ? cn23 : cn01;

            // --- post-reduce: first lane achieving minVal, then its first r
            // (lowest global column index == jnp.argmin tie-break). bal != 0 by
            // construction (minVal is some lane's bestv; no NaNs in the data);
            // the iteration guard bounds any violation to a wrong answer.
            const unsigned long long bal = __ballot(bestv == minVal);
            const int fl  = __ffsll((long long)bal) - 1;
            const int jr  = rl(candr, fl);
            const int nxt = rl(candnxt, fl);
            const int j   = fl * 4 + jr;

            // mark column j scanned (hides under the next row load; no dep on it)
            #pragma unroll
            for (int r = 0; r < 4; ++r) {
                if (lane * 4 + r == j) scadd[r] = INFV;
            }

            if (nxt < 0) sink = j;
            else         i = nxt;
        }

        // dump sp for the dual-update gather (only per-outer LDS use)
        *reinterpret_cast<float4*>(&sp_s[lane * 4]) = make_float4(sp[0], sp[1], sp[2], sp[3]);
        __syncthreads();

        // ---- dual updates (select semantics, same elementwise ops as reference).
        // Note: the sink column's scadd may be unset (marked after break) — the
        // reference's v-update there is v -= (minVal - sp[sink]) = v -= 0, an
        // identity, so skipping it is exact.
        #pragma unroll
        for (int r = 0; r < 4; ++r) {
            const int row = lane * 4 + r;
            if ((SRm >> r) & 1) {
                float du;
                if (row == cur) {
                    du = minVal;
                } else {
                    int c = c4r[r];
                    c = c < 0 ? 0 : c;            // clip like reference
                    du = minVal - sp_s[c];
                }
                u[r] = u[r] + du;
            }
            if (scadd[r] != 0.0f) v[r] = v[r] - (minVal - sp[r]);   // scadd!=0 <=> SC
        }
        __syncthreads();

        // ---- augment along alternating path (wave-uniform walk, registers) ----
        {
            int j = sink;
            for (int guard = 0; guard < NN; ++guard) {
                const int ii = read4i(path, j);
                write4i(r4c, j, ii, lane);
                const int jn = read4i(c4r, ii);
                write4i(c4r, ii, j, lane);
                if (ii == cur) break;
                j = jn;
            }
        }
    }

    // ---- emit output ----
    int* ob = out + b * NN;
    #pragma unroll
    for (int r = 0; r < 4; ++r) {
        const int row = lane * 4 + r;
        if (row < n) ob[row] = c4r[r];
        tmp_s[lane * 4 + r] = r4c[r];
    }
    __syncthreads();
    if (lane == 0) {
        int cnt = 0;
        for (int c = 0; c < NN; ++c) {
            if (tmp_s[c] >= n) {      // column assigned to an invalid row => unused
                ob[n + cnt] = c;
                ++cnt;
            }
        }
    }
}

extern "C" void kernel_launch(void* const* d_in, const int* in_sizes, int n_in,
                              void* d_out, int out_size, void* d_ws, size_t ws_size,
                              hipStream_t stream) {
    const float* costs = (const float*)d_in[0];
    const void*  mask  = d_in[1];
    int*         out   = (int*)d_out;

    const int B = in_sizes[1] / NN;   // in_sizes[1] = B*N
    const size_t need = (size_t)B * NN * NN * sizeof(float);

    if (ws_size >= need && d_ws != nullptr) {
        float* ws = (float*)d_ws;
        transpose_mask_kernel<<<dim3(NN / 32, NN / 32, B), dim3(32, 8), 0, stream>>>(costs, mask, ws);

        // 158-row (158 KB) LDS row cache: 158*1024 + 2 KB static = 160 KB exactly.
        // hipFuncSetAttribute is host-side (graph-capture safe); fall back to 60
        // rows if rejected.
        int rcache = 158;
        hipError_t e = hipFuncSetAttribute(
            reinterpret_cast<const void*>(&lap_kernel<true>),
            hipFuncAttributeMaxDynamicSharedMemorySize,
            rcache * NN * (int)sizeof(float));
        if (e != hipSuccess) rcache = 60;
        const size_t dynbytes = (size_t)rcache * NN * sizeof(float);

        lap_kernel<true><<<dim3(B), dim3(64), dynbytes, stream>>>(costs, mask, ws, out, rcache);
    } else {
        lap_kernel<false><<<dim3(B), dim3(64), 0, stream>>>(costs, mask, nullptr, out, 0);
    }
}

// Round 10
// 4701.692 us; speedup vs baseline: 1.5289x; 1.0253x over previous
//
#include <hip/hip_runtime.h>

#define NN 256
#define INFV 1e30f

// ---- mask format handling (bool may arrive as bytes, int32, or float32) ----
__device__ __forceinline__ int mask_fmt(const void* m) {
    int w0 = ((const int*)m)[0];          // mask[0][0] is always true (lengths >= N/2)
    if (w0 == 1) return 0;                // int32 0/1
    if (w0 == 0x3F800000) return 1;       // float32 1.0f
    return 2;                             // 1-byte bool
}
__device__ __forceinline__ bool mask_at(const void* m, int fmt, int idx) {
    if (fmt == 0) return ((const int*)m)[idx] != 0;
    if (fmt == 1) return ((const float*)m)[idx] != 0.0f;
    return ((const unsigned char*)m)[idx] != 0;
}

// ---- tiled transpose + mask: ws[b][i][j] = mask[b][i] ? costs[b][j][i] : 0 ----
__global__ void transpose_mask_kernel(const float* __restrict__ costs,
                                      const void* __restrict__ mask,
                                      float* __restrict__ ws) {
    __shared__ float tile[32][33];
    const int b  = blockIdx.z;
    const int i0 = blockIdx.x * 32;
    const int j0 = blockIdx.y * 32;
    const int tx = threadIdx.x;   // 0..31
    const int ty = threadIdx.y;   // 0..7
    const int fmt = mask_fmt(mask);
    const float* Cb = costs + (size_t)b * NN * NN;
    float* Wb = ws + (size_t)b * NN * NN;

    #pragma unroll
    for (int k = 0; k < 32; k += 8) {
        tile[ty + k][tx] = Cb[(size_t)(j0 + ty + k) * NN + (i0 + tx)];
    }
    __syncthreads();
    #pragma unroll
    for (int k = 0; k < 32; k += 8) {
        const int i = i0 + ty + k;
        const int j = j0 + tx;
        const bool mv = mask_at(mask, fmt, b * NN + i);
        Wb[(size_t)i * NN + j] = mv ? tile[tx][ty + k] : 0.0f;
    }
}

// ---------- cross-lane helpers ----------
__device__ __forceinline__ int rl(int v, int lane) {
    return __builtin_amdgcn_readlane(v, lane);
}
__device__ __forceinline__ float rlf(float v, int lane) {
    return __int_as_float(__builtin_amdgcn_readlane(__float_as_int(v), lane));
}
// read element idx (uniform, 0..255) from a distributed array: lane k holds elems 4k..4k+3
__device__ __forceinline__ int read4i(const int a[4], int idx) {
    const int lane = idx >> 2;
    const int v0 = rl(a[0], lane), v1 = rl(a[1], lane);
    const int v2 = rl(a[2], lane), v3 = rl(a[3], lane);
    const int lo = (idx & 1) ? v1 : v0;
    const int hi = (idx & 1) ? v3 : v2;
    return (idx & 2) ? hi : lo;
}
__device__ __forceinline__ float read4f(const float a[4], int idx) {
    const int lane = idx >> 2;
    const int v0 = rl(__float_as_int(a[0]), lane), v1 = rl(__float_as_int(a[1]), lane);
    const int v2 = rl(__float_as_int(a[2]), lane), v3 = rl(__float_as_int(a[3]), lane);
    const int lo = (idx & 1) ? v1 : v0;
    const int hi = (idx & 1) ? v3 : v2;
    return __int_as_float((idx & 2) ? hi : lo);
}
// write val to distributed array element idx (idx uniform)
__device__ __forceinline__ void write4i(int (&a)[4], int idx, int val, int lane) {
    if (lane == (idx >> 2)) {
        switch (idx & 3) {
            case 0: a[0] = val; break;
            case 1: a[1] = val; break;
            case 2: a[2] = val; break;
            default: a[3] = val; break;
        }
    }
}

// DPP move: result = src from DPP-selected lane; lanes with no valid source keep old(=x)
template <int CTRL>
__device__ __forceinline__ float dpp_mov_f(float x) {
    return __int_as_float(__builtin_amdgcn_update_dpp(
        __float_as_int(x), __float_as_int(x), CTRL, 0xf, 0xf, false));
}
// full-wave min: row_shr 1,2,4,8 accumulates toward lane 15/31/47/63 of each 16-row;
// row_bcast:15 merges row pairs, row_bcast:31 merges halves (lane 63 <- global min).
__device__ __forceinline__ float wave_min64(float x) {
    x = fminf(x, dpp_mov_f<0x111>(x));  // row_shr:1
    x = fminf(x, dpp_mov_f<0x112>(x));  // row_shr:2
    x = fminf(x, dpp_mov_f<0x114>(x));  // row_shr:4
    x = fminf(x, dpp_mov_f<0x118>(x));  // row_shr:8
    x = fminf(x, dpp_mov_f<0x142>(x));  // row_bcast:15
    x = fminf(x, dpp_mov_f<0x143>(x));  // row_bcast:31
    return rlf(x, 63);
}

// ---- exact JV LAP, one block (1 wave, 64 lanes) per batch, 4 cols/lane ----
// rcache = number of leading rows of the (transposed+masked) cost matrix held in
// dynamic LDS (populated in the prologue). 0 disables the cache.
template <bool USE_WS>
__global__ __launch_bounds__(64)
void lap_kernel(const float* __restrict__ costs,
                const void* __restrict__ mask,
                const float* __restrict__ cmat,
                int* __restrict__ out,
                int rcache) {
    extern __shared__ float ldsrows[];   // [rcache][NN]

    const int b    = blockIdx.x;
    const int lane = threadIdx.x;   // lane owns rows/cols lane*4 .. lane*4+3

    __shared__ float sp_s[NN];
    __shared__ int   tmp_s[NN];

    const int fmt = mask_fmt(mask);

    // n = count of valid objects (mask is prefix-true)
    int nloc = 0;
    #pragma unroll
    for (int r = 0; r < 4; ++r)
        nloc += mask_at(mask, fmt, b * NN + lane * 4 + r) ? 1 : 0;
    #pragma unroll
    for (int off = 32; off; off >>= 1) nloc += __shfl_xor(nloc, off);
    const int n  = nloc;
    const int ns = __builtin_amdgcn_readfirstlane(n);  // SGPR -> scalar branches

    // distributed state (registers): lane k holds element 4k+r
    float u[4]  = {0.f, 0.f, 0.f, 0.f};   // row potentials
    float v[4]  = {0.f, 0.f, 0.f, 0.f};   // col potentials
    int  c4r[4] = {-1, -1, -1, -1};       // col4row (by row)
    int  r4c[4] = {-1, -1, -1, -1};       // row4col (by col)

    const float* CM = cmat + (size_t)b * NN * NN;   // transposed+masked
    const float* CB = costs + (size_t)b * NN * NN;  // raw (fallback)

    // ---- prologue: stage leading rows into LDS (one row per iteration) ----
    if (USE_WS) {
        #pragma unroll 4
        for (int row = 0; row < rcache; ++row) {
            const int base = row * NN + lane * 4;
            *reinterpret_cast<float4*>(&ldsrows[base]) =
                *reinterpret_cast<const float4*>(CM + base);
        }
        __syncthreads();
    }

    for (int cur = 0; cur < NN; ++cur) {
        // ---- Dijkstra shortest augmenting path (value-exact vs reference) ----
        // scadd: 0 normal / 1e30 once the column is scanned (the SC flag).
        //   rrm = rr + scadd: scanned -> exactly 1e30 (|rr| << ulp(1e30))
        //   sp  = fmin(sp, rrm): scanned cols stay frozen (== reference no-update)
        //   m   = sp + scadd: scanned -> exactly 1e30 (== reference INF), else sp
        float sp[4]    = {INFV, INFV, INFV, INFV};
        float scadd[4] = {0.f, 0.f, 0.f, 0.f};
        int  path[4]   = {-1, -1, -1, -1};
        int   SRm = 0;                    // per-lane 4-bit visited-rows mask
        int   i      = cur;               // wave-uniform (SGPR)
        float minVal = 0.0f;              // wave-uniform
        int   sink   = -1;

        // terminates within NN iterations (each adds a col to SC and an
        // unmatched col always exists); guard turns bugs into wrong answers,
        // never hangs.
        for (int guard = 0; guard <= NN && sink < 0; ++guard) {
            if (lane == (i >> 2)) SRm |= 1 << (i & 3);

            // row load; i is wave-uniform SGPR, ns/rcache are SGPR => all three
            // branches are scalar (s_cmp + s_cbranch). Rows >= ns are exactly
            // zero in CM (mask is prefix-true) -> skip the memory access.
            float cc[4];
            if (USE_WS) {
                if (i >= ns) {
                    cc[0] = cc[1] = cc[2] = cc[3] = 0.0f;
                } else if (i < rcache) {
                    const float4 c4 = *reinterpret_cast<const float4*>(&ldsrows[i * NN + lane * 4]);
                    cc[0] = c4.x; cc[1] = c4.y; cc[2] = c4.z; cc[3] = c4.w;
                } else {
                    const float4 c4 = *reinterpret_cast<const float4*>(CM + (size_t)i * NN + lane * 4);
                    cc[0] = c4.x; cc[1] = c4.y; cc[2] = c4.z; cc[3] = c4.w;
                }
            } else {
                if (i < ns) {
                    #pragma unroll
                    for (int r = 0; r < 4; ++r)
                        cc[r] = CB[(size_t)(lane * 4 + r) * NN + i];
                } else {
                    #pragma unroll
                    for (int r = 0; r < 4; ++r) cc[r] = 0.0f;
                }
            }
            const float u_i = read4f(u, i);   // uniform scalar; hides under load

            float m[4];
            #pragma unroll
            for (int r = 0; r < 4; ++r) {
                // exact reference op order: ((minVal + c) - u_i) - v_j
                const float rr  = minVal + cc[r] - u_i - v[r];
                const float rrm = rr + scadd[r];          // INF-masked like reference
                const bool upd = rrm < sp[r];             // strict <; false once scanned
                path[r] = upd ? i : path[r];
                sp[r]   = fminf(sp[r], rrm);              // frozen once scanned
                m[r]    = sp[r] + scadd[r];               // masked sp (1e30 if scanned)
            }

            // wave-wide min of m (value), broadcast to all lanes
            const float bestv = fminf(fminf(fminf(m[0], m[1]), m[2]), m[3]);
            minVal = wave_min64(bestv);

            // --- speculation, runs in parallel with the DPP reduce chain: this
            // lane's first-index candidate and its r4c value; both valid exactly
            // for the lane that wins the ballot below.
            int candr = 3;
            if (m[2] == bestv) candr = 2;
            if (m[1] == bestv) candr = 1;
            if (m[0] == bestv) candr = 0;
            const int cn01 = (candr & 1) ? r4c[1] : r4c[0];
            const int cn23 = (candr & 1) ? r4c[3] : r4c[2];
            const int candnxt = (candr & 2) ? cn23 : cn01;

            // --- post-reduce: first lane achieving minVal, then its first r
            // (lowest global column index == jnp.argmin tie-break). bal != 0 by
            // construction (minVal is some lane's bestv; no NaNs in the data);
            // the iteration guard bounds any violation to a wrong answer.
            const unsigned long long bal = __ballot(bestv == minVal);
            const int fl  = __ffsll((long long)bal) - 1;
            const int jr  = rl(candr, fl);
            const int nxt = rl(candnxt, fl);
            const int j   = fl * 4 + jr;

            // mark column j scanned (hides under the next row load; no dep on it)
            #pragma unroll
            for (int r = 0; r < 4; ++r) {
                if (lane * 4 + r == j) scadd[r] = INFV;
            }

            if (nxt < 0) sink = j;
            else         i = nxt;
        }

        // dump sp for the dual-update gather (only per-outer LDS use)
        *reinterpret_cast<float4*>(&sp_s[lane * 4]) = make_float4(sp[0], sp[1], sp[2], sp[3]);
        __syncthreads();

        // ---- dual updates (select semantics, same elementwise ops as reference).
        // Note: the sink column's scadd may be unset (marked after break) — the
        // reference's v-update there is v -= (minVal - sp[sink]) = v -= 0, an
        // identity, so skipping it is exact.
        #pragma unroll
        for (int r = 0; r < 4; ++r) {
            const int row = lane * 4 + r;
            if ((SRm >> r) & 1) {
                float du;
                if (row == cur) {
                    du = minVal;
                } else {
                    int c = c4r[r];
                    c = c < 0 ? 0 : c;            // clip like reference
                    du = minVal - sp_s[c];
                }
                u[r] = u[r] + du;
            }
            if (scadd[r] != 0.0f) v[r] = v[r] - (minVal - sp[r]);   // scadd!=0 <=> SC
        }
        __syncthreads();

        // ---- augment along alternating path (wave-uniform walk, registers) ----
        {
            int j = sink;
            for (int guard = 0; guard < NN; ++guard) {
                const int ii = read4i(path, j);
                write4i(r4c, j, ii, lane);
                const int jn = read4i(c4r, ii);
                write4i(c4r, ii, j, lane);
                if (ii == cur) break;
                j = jn;
            }
        }
    }

    // ---- emit output ----
    int* ob = out + b * NN;
    #pragma unroll
    for (int r = 0; r < 4; ++r) {
        const int row = lane * 4 + r;
        if (row < n) ob[row] = c4r[r];
        tmp_s[lane * 4 + r] = r4c[r];
    }
    __syncthreads();
    if (lane == 0) {
        int cnt = 0;
        for (int c = 0; c < NN; ++c) {
            if (tmp_s[c] >= n) {      // column assigned to an invalid row => unused
                ob[n + cnt] = c;
                ++cnt;
            }
        }
    }
}

extern "C" void kernel_launch(void* const* d_in, const int* in_sizes, int n_in,
                              void* d_out, int out_size, void* d_ws, size_t ws_size,
                              hipStream_t stream) {
    const float* costs = (const float*)d_in[0];
    const void*  mask  = d_in[1];
    int*         out   = (int*)d_out;

    const int B = in_sizes[1] / NN;   // in_sizes[1] = B*N
    const size_t need = (size_t)B * NN * NN * sizeof(float);

    if (ws_size >= need && d_ws != nullptr) {
        float* ws = (float*)d_ws;
        transpose_mask_kernel<<<dim3(NN / 32, NN / 32, B), dim3(32, 8), 0, stream>>>(costs, mask, ws);

        // 158-row (158 KB) LDS row cache: 158*1024 + 2 KB static = 160 KB exactly.
        // hipFuncSetAttribute is host-side (graph-capture safe); fall back to 60
        // rows if rejected.
        int rcache = 158;
        hipError_t e = hipFuncSetAttribute(
            reinterpret_cast<const void*>(&lap_kernel<true>),
            hipFuncAttributeMaxDynamicSharedMemorySize,
            rcache * NN * (int)sizeof(float));
        if (e != hipSuccess) rcache = 60;
        const size_t dynbytes = (size_t)rcache * NN * sizeof(float);

        lap_kernel<true><<<dim3(B), dim3(64), dynbytes, stream>>>(costs, mask, ws, out, rcache);
    } else {
        lap_kernel<false><<<dim3(B), dim3(64), 0, stream>>>(costs, mask, nullptr, out, 0);
    }
}